// Round 6
// baseline (662.423 us; speedup 1.0000x reference)
//
#include <hip/hip_runtime.h>
#include <hip/hip_bf16.h>

typedef __attribute__((ext_vector_type(8))) short short8;     // 8 bf16 / 16B
typedef __attribute__((ext_vector_type(4))) float f32x4;
typedef __attribute__((ext_vector_type(4))) unsigned int uint4v;

#define XSTRIDE 1856          // 29*64 floats per edge
#define CCH 64
// padded effective-weight layout (bf16): blk0 [512][448], blk1 [768][768], blk2 [640][640]
#define OFF1 229376
#define OFF2 819200
#define WTOT 1228800

__device__ __forceinline__ short f2bf(float f) {
    __hip_bfloat16 h = __float2bfloat16(f);
    return __builtin_bit_cast(short, h);
}

// ---------------- pass 1: effective bf16 weights ------------------------------------------
__global__ __launch_bounds__(256) void prep_weights(const float* __restrict__ W0,
                                                    const float* __restrict__ W1,
                                                    const float* __restrict__ W2,
                                                    short* __restrict__ ws) {
    int idx = blockIdx.x * 256 + threadIdx.x;
    if (idx < OFF1) {                       // [512][448], rows >=448 zero pad (unused now)
        ws[idx] = (idx < 448 * 448) ? f2bf(W0[idx]) : (short)0;
        return;
    }
    if (idx < OFF2) {
        int i = idx - OFF1;
        int n = i / 768, k = i % 768;
        int no = n / 384, ni = n % 384;
        int ki = k % 384;
        float v;
        if (no == (k / 384)) v =  W1[ni * 384 + ki];
        else if (no == 0)    v = -W1[(384 + ni) * 384 + ki];
        else                 v =  W1[(384 + ni) * 384 + ki];
        ws[idx] = f2bf(v);
        return;
    }
    if (idx < WTOT) {
        int i = idx - OFF2;
        int n = i / 640, k = i % 640;
        int no = n / 320, ni = n % 320;
        int ki = k % 320;
        float v;
        if (no == (k / 320)) v =  W2[ni * 320 + ki];
        else if (no == 0)    v = -W2[(320 + ni) * 320 + ki];
        else                 v =  W2[(320 + ni) * 320 + ki];
        ws[idx] = f2bf(v);
    }
}

// ---------------- pass 2: B-resident stripe GEMM, barrier-free k-loop ----------------------
// Block (512 thr = 8 waves) owns one 64-col output stripe (= one output m-row) and 4
// edge-groups of 512 edges (64 per wave). B slice [64 n][Kb] loaded to LDS ONCE (1 barrier
// total). K-loop: A straight from global to regs (coalesced 16B/lane), cvt f32->bf16 in
// reg, B via ds_read_b128 (compile-time offsets), 32 MFMA per g-row. No barriers -> the
// compiler pipelines loads across MFMA freely; latency hidden by ILP + 2 waves/SIMD.
template<int FAM>
__device__ __forceinline__ void run_family(short* __restrict__ Bl, int stripe_g, int eg4,
                                           const float* __restrict__ x,
                                           const float* __restrict__ b0,
                                           const short* __restrict__ wsW,
                                           float* __restrict__ out, int E) {
    constexpr int KB    = FAM == 0 ? 448 : FAM == 1 ? 768 : 640;
    constexpr int NGR   = KB / 64;
    constexpr int KBASE = FAM == 0 ? 0 : FAM == 1 ? 7 : 19;
    constexpr long WOFF = FAM == 0 ? 0 : FAM == 1 ? (long)OFF1 : (long)OFF2;
    constexpr int LSTR  = KB + 8;       // +16B pad: row shift 16B in bank space -> ~free
    constexpr int KB8   = KB / 8;
    constexpr int TOM[29] = {0,2,6,11,16,21,26, 3,7,12,17,22,27, 1,5,10,15,20,25,
                             8,13,18,23,28, 4,9,14,19,24};
    const int sl = stripe_g - KBASE;
    const int n0 = sl * 64;
    const int tid = threadIdx.x;

    // ---- B fill, once per block (coalesced 16B/lane reads, L2-hot) ----
    const short* Wb = wsW + WOFF + (size_t)n0 * KB;
#pragma unroll
    for (int it = 0; it < NGR; ++it) {          // NGR*512 == 64*KB/8 chunks exactly
        int flat = it * 512 + tid;
        int n = flat / KB8, kc = flat % KB8;
        *(uint4v*)&Bl[n * LSTR + kc * 8] = *(const uint4v*)(Wb + (size_t)n * KB + kc * 8);
    }
    __syncthreads();                            // the ONLY barrier in this kernel

    const int w = tid >> 6, lane = tid & 63;
    const int lrow = lane & 15, lk = lane >> 4;
    const int lp = TOM[stripe_g];               // output lp-row for this stripe

    int bbase[4];
#pragma unroll
    for (int nf = 0; nf < 4; ++nf) bbase[nf] = (nf * 16 + lrow) * LSTR + lk * 8;

    float bias[4] = {0.f, 0.f, 0.f, 0.f};
    if (FAM == 0) {
#pragma unroll
        for (int nf = 0; nf < 4; ++nf) bias[nf] = b0[n0 + nf * 16 + lrow];
    }

    for (int eo = 0; eo < 4; ++eo) {
        int egroup = eg4 * 4 + eo;
        if (egroup * 512 >= E) break;
        const int eb = egroup * 512 + w * 64;

        const float* pa[4];
#pragma unroll
        for (int mf = 0; mf < 4; ++mf) {
            int e = eb + mf * 16 + lrow;
            if (e >= E) e = E - 1;              // clamp: loads valid, rows never stored
            pa[mf] = x + (size_t)e * XSTRIDE + lk * 8;
        }

        f32x4 acc[4][4] = {};
#pragma unroll
        for (int gi = 0; gi < NGR; ++gi) {
            const int g = TOM[KBASE + gi];      // compile-time under full unroll
#pragma unroll
            for (int ks = 0; ks < 2; ++ks) {
                short8 af[4], bf[4];
#pragma unroll
                for (int mf = 0; mf < 4; ++mf) {
                    f32x4 lo = *(const f32x4*)(pa[mf] + g * 64 + ks * 32);
                    f32x4 hi = *(const f32x4*)(pa[mf] + g * 64 + ks * 32 + 4);
                    short8 v;
#pragma unroll
                    for (int j = 0; j < 4; ++j) { v[j] = f2bf(lo[j]); v[4 + j] = f2bf(hi[j]); }
                    af[mf] = v;
                }
#pragma unroll
                for (int nf = 0; nf < 4; ++nf)
                    bf[nf] = *(const short8*)&Bl[bbase[nf] + gi * 64 + ks * 32];
#pragma unroll
                for (int mf = 0; mf < 4; ++mf)
#pragma unroll
                    for (int nf = 0; nf < 4; ++nf)
                        acc[mf][nf] = __builtin_amdgcn_mfma_f32_16x16x32_bf16(af[mf], bf[nf], acc[mf][nf], 0, 0, 0);
            }
        }

        // store: D col = lrow (lane&15), row = lk*4+j (m89 layout)
#pragma unroll
        for (int mf = 0; mf < 4; ++mf) {
#pragma unroll
            for (int j = 0; j < 4; ++j) {
                int e = eb + mf * 16 + lk * 4 + j;
                if (e < E) {
                    float* op = out + (size_t)e * XSTRIDE + lp * 64 + lrow;
#pragma unroll
                    for (int nf = 0; nf < 4; ++nf)
                        op[nf * 16] = acc[mf][nf][j] + bias[nf];
                }
            }
        }
    }
}

__global__ __launch_bounds__(512) void so2_bres(const float* __restrict__ x,
                                                const float* __restrict__ b0,
                                                const short* __restrict__ wsW,
                                                float* __restrict__ out,
                                                int E, int nb) {
    __shared__ short Bl[64 * 776];              // 99328 B (max: blk1 64 x (768+8))

    // bijective XCD chunking: consecutive wgid (same eg4, all 29 stripes) share an XCD
    int bid = blockIdx.x;
    int q = nb >> 3, r = nb & 7;
    int xcd = bid & 7, pos = bid >> 3;
    int cnt = q + (xcd < r ? 1 : 0);
    if (pos >= cnt) return;
    int base = (xcd < r) ? xcd * (q + 1) : r * (q + 1) + (xcd - r) * q;
    int wgid = base + pos;

    int eg4 = wgid / 29, stripe = wgid % 29;
    if (stripe < 7)       run_family<0>(Bl, stripe, eg4, x, b0, wsW, out, E);
    else if (stripe < 19) run_family<1>(Bl, stripe, eg4, x, b0, wsW, out, E);
    else                  run_family<2>(Bl, stripe, eg4, x, b0, wsW, out, E);
}

extern "C" void kernel_launch(void* const* d_in, const int* in_sizes, int n_in,
                              void* d_out, int out_size, void* d_ws, size_t ws_size,
                              hipStream_t stream) {
    const float* x_emb = (const float*)d_in[0];
    // d_in[1] = x_edge: unused by the reference
    const float* W0 = (const float*)d_in[2];
    const float* b0 = (const float*)d_in[3];
    const float* W1 = (const float*)d_in[4];
    const float* W2 = (const float*)d_in[5];
    float* out = (float*)d_out;
    short* ws  = (short*)d_ws;     // 2.46 MB effective bf16 weights

    const int E = in_sizes[0] / (29 * CCH);
    const int neg  = (E + 511) / 512;           // 512-edge groups
    const int eg4c = (neg + 3) / 4;             // 4 egroups per block
    const int nb   = 29 * eg4c;                 // useful blocks
    const int grid = ((nb + 7) / 8) * 8;        // XCD-chunk padding; extras return

    prep_weights<<<(WTOT + 255) / 256, 256, 0, stream>>>(W0, W1, W2, ws);
    so2_bres<<<grid, 512, 0, stream>>>(x_emb, b0, (const short*)ws, out, E, nb);
}

// Round 8
// 574.539 us; speedup vs baseline: 1.1530x; 1.1530x over previous
//
#include <hip/hip_runtime.h>
#include <hip/hip_bf16.h>

typedef __attribute__((ext_vector_type(8))) short short8;     // 8 bf16 / 16B
typedef __attribute__((ext_vector_type(4))) float f32x4;
typedef __attribute__((ext_vector_type(4))) unsigned int uint4v;

#define XSTRIDE 1856          // 29*64 floats per edge
#define CCH 64
// padded effective-weight layout (bf16): blk0 [512][448], blk1 [768][768], blk2 [640][640]
#define OFF1 229376
#define OFF2 819200
#define WTOT 1228800

__device__ __forceinline__ short f2bf(float f) {
    __hip_bfloat16 h = __float2bfloat16(f);
    return __builtin_bit_cast(short, h);
}

// ---------------- pass 1: effective bf16 weights ------------------------------------------
__global__ __launch_bounds__(256) void prep_weights(const float* __restrict__ W0,
                                                    const float* __restrict__ W1,
                                                    const float* __restrict__ W2,
                                                    short* __restrict__ ws) {
    int idx = blockIdx.x * 256 + threadIdx.x;
    if (idx < OFF1) {                       // [512][448], rows >=448 zero pad (unused)
        ws[idx] = (idx < 448 * 448) ? f2bf(W0[idx]) : (short)0;
        return;
    }
    if (idx < OFF2) {
        int i = idx - OFF1;
        int n = i / 768, k = i % 768;
        int no = n / 384, ni = n % 384;
        int ki = k % 384;
        float v;
        if (no == (k / 384)) v =  W1[ni * 384 + ki];
        else if (no == 0)    v = -W1[(384 + ni) * 384 + ki];
        else                 v =  W1[(384 + ni) * 384 + ki];
        ws[idx] = f2bf(v);
        return;
    }
    if (idx < WTOT) {
        int i = idx - OFF2;
        int n = i / 640, k = i % 640;
        int no = n / 320, ni = n % 320;
        int ki = k % 320;
        float v;
        if (no == (k / 320)) v =  W2[ni * 320 + ki];
        else if (no == 0)    v = -W2[(320 + ni) * 320 + ki];
        else                 v =  W2[(320 + ni) * 320 + ki];
        ws[idx] = f2bf(v);
    }
}

// ---------------- pass 2: B-resident stripe GEMM, explicit depth-3 reg pipeline -------------
// Block (512 thr = 8 waves) owns one 64-col output stripe and 512 edges (64/wave).
// B slice [64 n][Kb] -> LDS once (the only barrier). K fully unrolled in half-steps
// (32 ch); body h: cvt buf[h%3] -> X frag (counted per-register vmcnt wait), REISSUE
// loads for h+3 into the freed buffer, ds_read W frags, 16 MFMA. ~16KB/wave in flight.
// Operand swap: W is MFMA A-operand -> D rows = n -> contiguous 16B f32x4 stores.
template<int FAM>
__device__ __forceinline__ void run_family(short* __restrict__ Bl, int stripe_g, int eg,
                                           const float* __restrict__ x,
                                           const float* __restrict__ b0,
                                           const short* __restrict__ wsW,
                                           float* __restrict__ out, int E) {
    constexpr int KB    = FAM == 0 ? 448 : FAM == 1 ? 768 : 640;
    constexpr int NGR   = KB / 64;
    constexpr int H     = 2 * NGR;          // half-steps: 14 / 24 / 20
    constexpr int KBASE = FAM == 0 ? 0 : FAM == 1 ? 7 : 19;
    constexpr long WOFF = FAM == 0 ? 0 : FAM == 1 ? (long)OFF1 : (long)OFF2;
    constexpr int LSTR  = KB + 8;
    constexpr int KB8   = KB / 8;
    constexpr int TOM[29] = {0,2,6,11,16,21,26, 3,7,12,17,22,27, 1,5,10,15,20,25,
                             8,13,18,23,28, 4,9,14,19,24};
    const int sl = stripe_g - KBASE;
    const int tid = threadIdx.x;

    // ---- B fill, once per block ----
    const short* Wb = wsW + WOFF + (size_t)(sl * 64) * KB;
#pragma unroll
    for (int it = 0; it < NGR; ++it) {      // NGR*512 == 64*KB/8 chunks exactly
        int flat = it * 512 + tid;
        int n = flat / KB8, kc = flat % KB8;
        *(uint4v*)&Bl[n * LSTR + kc * 8] = *(const uint4v*)(Wb + (size_t)n * KB + kc * 8);
    }
    __syncthreads();                        // the ONLY barrier

    const int w = tid >> 6, lane = tid & 63;
    const int lrow = lane & 15, lk = lane >> 4;
    const int eb = eg * 512 + w * 64;

    const float* pe[4];
#pragma unroll
    for (int ef = 0; ef < 4; ++ef) {
        int e = eb + ef * 16 + lrow;
        if (e >= E) e = E - 1;              // clamp loads; stores guarded below
        pe[ef] = x + (size_t)e * XSTRIDE + lk * 8;
    }

    f32x4 acc[4][4] = {};                   // [ef][nf]
    f32x4 L0[8], L1[8], L2[8];              // depth-3 staging, all statically indexed

    auto LOADH = [&](int hh, f32x4* Lb) {
        // hh is a compile-time constant after full unroll -> off_ folds to an immediate
        int off_ = TOM[KBASE + (hh >> 1)] * 64 + (hh & 1) * 32;
#pragma unroll
        for (int ef = 0; ef < 4; ++ef) {
            Lb[2 * ef]     = *(const f32x4*)(pe[ef] + off_);
            Lb[2 * ef + 1] = *(const f32x4*)(pe[ef] + off_ + 4);
        }
    };

    LOADH(0, L0);
    LOADH(1, L1);
    LOADH(2, L2);

#pragma unroll
    for (int h = 0; h < H; ++h) {
        f32x4* C = (h % 3 == 0) ? L0 : (h % 3 == 1) ? L1 : L2;   // static after unroll
        // consume: f32 -> bf16 X fragment (waits only on THIS buffer's 8 loads)
        short8 bfx[4];
#pragma unroll
        for (int ef = 0; ef < 4; ++ef) {
            short8 v;
#pragma unroll
            for (int j = 0; j < 4; ++j) {
                v[j]     = f2bf(C[2 * ef][j]);
                v[4 + j] = f2bf(C[2 * ef + 1][j]);
            }
            bfx[ef] = v;
        }
        // reissue into the freed buffer: loads for half-step h+3
        if (h + 3 < H) LOADH(h + 3, C);
        // W fragments from LDS
        short8 af[4];
#pragma unroll
        for (int nf = 0; nf < 4; ++nf)
            af[nf] = *(const short8*)&Bl[(nf * 16 + lrow) * LSTR + (h >> 1) * 64 + (h & 1) * 32 + lk * 8];
#pragma unroll
        for (int ef = 0; ef < 4; ++ef)
#pragma unroll
            for (int nf = 0; nf < 4; ++nf)
                acc[ef][nf] = __builtin_amdgcn_mfma_f32_16x16x32_bf16(af[nf], bfx[ef], acc[ef][nf], 0, 0, 0);
    }

    // stores: per (ef,nf) one f32x4 at n = nf*16 + lk*4, edge = eb + ef*16 + lrow
    const int lp = TOM[stripe_g];
#pragma unroll
    for (int ef = 0; ef < 4; ++ef) {
        int e = eb + ef * 16 + lrow;
        if (e < E) {
            float* op = out + (size_t)e * XSTRIDE + lp * 64 + lk * 4;
#pragma unroll
            for (int nf = 0; nf < 4; ++nf) {
                f32x4 v = acc[ef][nf];
                if (FAM == 0) {
                    f32x4 bv = *(const f32x4*)(b0 + sl * 64 + nf * 16 + lk * 4);
                    v += bv;
                }
                *(f32x4*)(op + nf * 16) = v;
            }
        }
    }
}

__global__ __launch_bounds__(512, 1) void so2_bres(const float* __restrict__ x,
                                                   const float* __restrict__ b0,
                                                   const short* __restrict__ wsW,
                                                   float* __restrict__ out,
                                                   int E, int nb) {
    __shared__ short Bl[64 * 776];          // 99,328 B (blk1 max: 64 x (768+8))

    // bijective XCD chunking: consecutive wgid (one eg's 29 stripes) share an XCD's L2
    int bid = blockIdx.x;
    int q = nb >> 3, r = nb & 7;
    int xcd = bid & 7, pos = bid >> 3;
    int cnt = q + (xcd < r ? 1 : 0);
    if (pos >= cnt) return;
    int base = (xcd < r) ? xcd * (q + 1) : r * (q + 1) + (xcd - r) * q;
    int wgid = base + pos;

    int eg = wgid / 29, stripe = wgid % 29;
    if (stripe < 7)       run_family<0>(Bl, stripe, eg, x, b0, wsW, out, E);
    else if (stripe < 19) run_family<1>(Bl, stripe, eg, x, b0, wsW, out, E);
    else                  run_family<2>(Bl, stripe, eg, x, b0, wsW, out, E);
}

extern "C" void kernel_launch(void* const* d_in, const int* in_sizes, int n_in,
                              void* d_out, int out_size, void* d_ws, size_t ws_size,
                              hipStream_t stream) {
    const float* x_emb = (const float*)d_in[0];
    // d_in[1] = x_edge: unused by the reference
    const float* W0 = (const float*)d_in[2];
    const float* b0 = (const float*)d_in[3];
    const float* W1 = (const float*)d_in[4];
    const float* W2 = (const float*)d_in[5];
    float* out = (float*)d_out;
    short* ws  = (short*)d_ws;     // 2.46 MB effective bf16 weights

    const int E = in_sizes[0] / (29 * CCH);
    const int negs = (E + 511) / 512;       // 512-edge groups, one per block
    const int nb   = negs * 29;             // 29 stripes each
    const int grid = ((nb + 7) / 8) * 8;    // XCD-chunk padding; extras return

    prep_weights<<<(WTOT + 255) / 256, 256, 0, stream>>>(W0, W1, W2, ws);
    so2_bres<<<grid, 512, 0, stream>>>(x_emb, b0, (const short*)ws, out, E, nb);
}

// Round 9
// 422.812 us; speedup vs baseline: 1.5667x; 1.3589x over previous
//
#include <hip/hip_runtime.h>
#include <hip/hip_bf16.h>

typedef __attribute__((ext_vector_type(8))) short short8;     // 8 bf16 / 16B
typedef __attribute__((ext_vector_type(4))) float f32x4;

#define XSTRIDE 1856          // 29*64 floats per edge
// padded effective-weight layout (bf16): blk0 [512][448], blk1 [768][768], blk2 [640][640]
#define OFF1 229376
#define OFF2 819200
#define WTOT 1228800

__device__ __forceinline__ short f2bf(float f) {
    __hip_bfloat16 h = __float2bfloat16(f);
    return __builtin_bit_cast(short, h);
}

__device__ __forceinline__ void load16_lds(const void* g, void* l) {
    __builtin_amdgcn_global_load_lds((const __attribute__((address_space(1))) unsigned int*)g,
                                     (__attribute__((address_space(3))) unsigned int*)l, 16, 0, 0);
}

// ---------------- pass 1: effective bf16 weights (blk0 zero-padded to 512 rows) -------------
__global__ __launch_bounds__(256) void prep_weights(const float* __restrict__ W0,
                                                    const float* __restrict__ W1,
                                                    const float* __restrict__ W2,
                                                    short* __restrict__ ws) {
    int idx = blockIdx.x * 256 + threadIdx.x;
    if (idx < OFF1) {                       // [512][448], rows >=448 zero pad
        ws[idx] = (idx < 448 * 448) ? f2bf(W0[idx]) : (short)0;
        return;
    }
    if (idx < OFF2) {
        int i = idx - OFF1;
        int n = i / 768, k = i % 768;
        int no = n / 384, ni = n % 384;
        int ki = k % 384;
        float v;
        if (no == (k / 384)) v =  W1[ni * 384 + ki];
        else if (no == 0)    v = -W1[(384 + ni) * 384 + ki];
        else                 v =  W1[(384 + ni) * 384 + ki];
        ws[idx] = f2bf(v);
        return;
    }
    if (idx < WTOT) {
        int i = idx - OFF2;
        int n = i / 640, k = i % 640;
        int no = n / 320, ni = n % 320;
        int ki = k % 320;
        float v;
        if (no == (k / 320)) v =  W2[ni * 320 + ki];
        else if (no == 0)    v = -W2[(320 + ni) * 320 + ki];
        else                 v =  W2[(320 + ni) * 320 + ki];
        ws[idx] = f2bf(v);
    }
}

// ---------------- pass 2: column-split GEMM -------------------------------------------------
// Block: 512 thr / 8 waves, ONE family, 64 edges. Waves split family-N: wave w owns cols
// [w*NW, (w+1)*NW). x is read ONCE (families' K-slices are disjoint). A k-tile (64e x 64ch
// f32, 16 KB) staged via global_load_lds into a QUAD buffer (64 KB LDS), issue depth 2,
// one counted s_waitcnt vmcnt(2) + one raw s_barrier per phase. Source-chunk XOR swizzle
// spreads frag-read banks. B (weights, L2-resident) loaded global->reg as MFMA frags with
// ROLLING reissue inside the MFMA loop (WAR reg dependency pins placement -> spread issue).
template<int FAM>
__device__ __forceinline__ void run_cs(float* __restrict__ Ab, int eg,
                                       const float* __restrict__ x,
                                       const float* __restrict__ b0,
                                       const short* __restrict__ wsW,
                                       float* __restrict__ out, int E) {
    constexpr int KB    = FAM == 0 ? 448 : FAM == 1 ? 768 : 640;
    constexpr int NK    = KB / 64;                       // 7 / 12 / 10 phases
    constexpr int KBASE = FAM == 0 ? 0 : FAM == 1 ? 7 : 19;
    constexpr long WOFF = FAM == 0 ? 0 : FAM == 1 ? (long)OFF1 : (long)OFF2;
    constexpr int NW    = FAM == 0 ? 64 : FAM == 1 ? 96 : 80;   // cols per wave (fam0 padded)
    constexpr int NF    = NW / 16;                       // 4 / 6 / 5 col-frags
    constexpr int TOM[29] = {0,2,6,11,16,21,26, 3,7,12,17,22,27, 1,5,10,15,20,25,
                             8,13,18,23,28, 4,9,14,19,24};

    const int tid  = threadIdx.x;
    const int w    = tid >> 6, lane = tid & 63;
    const int lrow = lane & 15, lk = lane >> 4;
    const int eb   = eg * 64;
    const short* Wb = wsW + WOFF;
    const int n0   = w * NW;

    // ---- A staging (wave w, issue j covers edges 8w+4j..+3; lane: edge +lk, slot lrow) ----
    // LDS slot s of edge e holds source chunk s^(e&7); e&7 = 4j+lk (w*8 drops out).
    auto stageA = [&](int kt, int buf) {
        const int g = TOM[KBASE + kt];
#pragma unroll
        for (int j = 0; j < 2; ++j) {
            int e  = 8 * w + 4 * j + lk;
            int ge = eb + e; if (ge >= E) ge = E - 1;    // clamp: rows never stored
            int c  = lrow ^ (4 * j + lk);                // swizzled source chunk
            const float* src = x + (size_t)ge * XSTRIDE + g * 64 + c * 4;
            load16_lds(src, (char*)(Ab + buf * 4096 + (8 * w + 4 * j) * 64) + lane * 16);
        }
    };
    // ---- B frag loader: W[n][k] row-major, lane&15 = n-row, 16B contiguous k (L2-hot) ----
    auto bload = [&](int kt, int nf, int kh) -> short8 {
        return *(const short8*)(Wb + (size_t)(n0 + nf * 16 + lrow) * KB + kt * 64 + kh * 32 + lk * 8);
    };

    f32x4  acc[4][NF] = {};
    short8 bfrag[NF][2];

    stageA(0, 0);
    stageA(1, 1);
#pragma unroll
    for (int nf = 0; nf < NF; ++nf) {
        bfrag[nf][0] = bload(0, nf, 0);
        bfrag[nf][1] = bload(0, nf, 1);
    }

    for (int kt = 0; kt < NK; ++kt) {
        const int buf = kt & 3;
        if (kt + 2 < NK) {
            stageA(kt + 2, (kt + 2) & 3);
            // queue: A(kt+1)^2 [phase kt-1], B(kt)^2NF [rolled], A(kt+2)^2 [now]
            asm volatile("s_waitcnt vmcnt(2)" ::: "memory");
        } else {
            asm volatile("s_waitcnt vmcnt(0)" ::: "memory");
        }
        __builtin_amdgcn_s_barrier();          // everyone's A(kt) landed; buf reuse safe (Q=4)
        __builtin_amdgcn_sched_barrier(0);

#pragma unroll
        for (int kh = 0; kh < 2; ++kh) {
            // X frags for this k-half: LDS f32 (swizzled slots) -> cvt bf16
            short8 bfx[4];
#pragma unroll
            for (int ef = 0; ef < 4; ++ef) {
                int e = ef * 16 + lrow;
                const float* base = Ab + buf * 4096 + e * 64;
                int p  = lrow & 7;
                int c0 = kh * 8 + lk * 2;
                f32x4 lo = *(const f32x4*)(base + ((c0) ^ p) * 4);
                f32x4 hi = *(const f32x4*)(base + ((c0 + 1) ^ p) * 4);
                short8 v;
#pragma unroll
                for (int q = 0; q < 4; ++q) { v[q] = f2bf(lo[q]); v[4 + q] = f2bf(hi[q]); }
                bfx[ef] = v;
            }
#pragma unroll
            for (int nf = 0; nf < NF; ++nf) {
#pragma unroll
                for (int ef = 0; ef < 4; ++ef)
                    acc[ef][nf] = __builtin_amdgcn_mfma_f32_16x16x32_bf16(
                        bfrag[nf][kh], bfx[ef], acc[ef][nf], 0, 0, 0);
                // rolling reissue: after kh=1, bfrag[nf] fully consumed this phase.
                if (kh == 1 && kt + 1 < NK) {
                    bfrag[nf][0] = bload(kt + 1, nf, 0);
                    bfrag[nf][1] = bload(kt + 1, nf, 1);
                }
            }
        }
    }

    // ---- stores: D col = edge (lrow), rows = n (lk*4+j) -> contiguous f32x4 (R8-verified) --
#pragma unroll
    for (int ef = 0; ef < 4; ++ef) {
        int e = eb + ef * 16 + lrow;
        if (e < E) {
#pragma unroll
            for (int nf = 0; nf < NF; ++nf) {
                int ln = n0 + nf * 16;                   // family-n of this frag
                if (FAM != 0 || ln < 448) {              // fam0 pad cols: skip
                    int lp = TOM[KBASE + (ln >> 6)];
                    float* op = out + (size_t)e * XSTRIDE + lp * 64 + (ln & 63) + lk * 4;
                    f32x4 v = acc[ef][nf];
                    if (FAM == 0) v += *(const f32x4*)(b0 + ln + lk * 4);
                    *(f32x4*)op = v;
                }
            }
        }
    }
}

__global__ __launch_bounds__(512, 1) void so2_cs(const float* __restrict__ x,
                                                 const float* __restrict__ b0,
                                                 const short* __restrict__ wsW,
                                                 float* __restrict__ out, int E) {
    __shared__ float Ab[4 * 4096];                       // quad-buffered A tile, 64 KB
    int bid = blockIdx.x;
    int fam = bid % 3, eg = bid / 3;                     // family interleave balances XCDs
    if (fam == 0)      run_cs<0>(Ab, eg, x, b0, wsW, out, E);
    else if (fam == 1) run_cs<1>(Ab, eg, x, b0, wsW, out, E);
    else               run_cs<2>(Ab, eg, x, b0, wsW, out, E);
}

extern "C" void kernel_launch(void* const* d_in, const int* in_sizes, int n_in,
                              void* d_out, int out_size, void* d_ws, size_t ws_size,
                              hipStream_t stream) {
    const float* x_emb = (const float*)d_in[0];
    // d_in[1] = x_edge: unused by the reference
    const float* W0 = (const float*)d_in[2];
    const float* b0 = (const float*)d_in[3];
    const float* W1 = (const float*)d_in[4];
    const float* W2 = (const float*)d_in[5];
    float* out = (float*)d_out;
    short* ws  = (short*)d_ws;     // 2.46 MB effective bf16 weights

    const int E  = in_sizes[0] / XSTRIDE;
    const int eg = (E + 63) / 64;                        // 64-edge groups
    const int nb = 3 * eg;                               // one block per (family, egroup)

    prep_weights<<<(WTOT + 255) / 256, 256, 0, stream>>>(W0, W1, W2, ws);
    so2_cs<<<nb, 512, 0, stream>>>(x_emb, b0, (const short*)ws, out, E);
}